// Round 5
// baseline (2448.891 us; speedup 1.0000x reference)
//
#include <hip/hip_runtime.h>
#include <hip/hip_bf16.h>

// MCMambaLM: B=1, T=2048, D=768, K=8, V=1024, D_IN=1536, D_STATE=16,
// D_CONV=4, DT_RANK=48, L=4, SEG=256, n_seg=8.
// Round 10: resubmit of round 9 (container infra failure, no kernel signal).
// XCD swizzle removed (natural round-robin keeps per-XCD W panels L2-resident
// when gx%8==0; chunked swizzle thrashed L2: FETCH 55->275MB). All MFMA GEMMs
// at 128x64 tiles (24KB LDS) with conflict-free fragment-order staging.
// Producer-fused hi/lo splits kept.

#define T_LEN   2048
#define DMODEL  768
#define DIN     1536
#define DXZ     3072
#define NSTATE  16
#define DTRANK  48
#define FDIM    80
#define NSEG    8
#define SEGLEN  256
#define NHEADV  8192
#define CH      64
#define NC      32

// ---- f32 scratch ----
#define OFF_X     0u
#define OFF_XZ    1572864u
#define OFF_UC    7864320u
#define OFF_DBC   11010048u
#define OFF_DELTA 11173888u
#define OFF_Y     14319616u
#define OFF_XOUT  17465344u
#define OFF_URET  19038208u
#define OFF_MCUR  20611072u
#define OFF_MSTK  22183936u
#define OFF_WEMB  22190080u   // 8*1024*768
#define OFF_WCW   28481536u   // 4*1536*4
#define OFF_WCB   28506112u   // 4*1536
#define OFF_WXP   28512256u   // 4*80*1536
#define OFF_WDW   29003776u   // 4*1536*48
#define OFF_WDB   29298688u   // 4*1536
#define OFF_WAL   29304832u   // 4*1536*16
#define OFF_WDS   29403136u   // 4*1536
#define OFF_SLOC  29409280u   // NC*DIN*16
#define OFF_HIN   30195712u
#define OFF_CHP   30982144u   // NC*DIN
#define WS_TOTAL  31031296u
__device__ __align__(16) float g_ws[WS_TOTAL];

// ---- bf16 hi/lo scratch (ushort elems) ----
#define BF_XHI   0u          // 2048*768
#define BF_XLO   1572864u
#define BF_YHI   3145728u    // 2048*1536
#define BF_YLO   6291456u
#define BF_IPHI  9437184u    // 4*3072*768
#define BF_IPLO  18874368u
#define BF_OPHI  28311552u   // 4*768*1536
#define BF_OPLO  33030144u
#define BF_WUHI  37748736u   // 4*768*768
#define BF_WULO  40108032u
#define BF_HWHI  42467328u   // 8192*768
#define BF_HWLO  48758784u
#define BF_TOTAL 55050240u
__device__ __align__(16) unsigned short g_bf[BF_TOTAL];
__device__ unsigned int g_isbf16;

typedef __attribute__((ext_vector_type(8))) short bf16x8;
typedef __attribute__((ext_vector_type(4))) float f32x4;

__device__ __forceinline__ float bf2f(unsigned short u) {
  union { unsigned int i; float f; } c; c.i = ((unsigned int)u) << 16; return c.f;
}
__device__ __forceinline__ unsigned short f2bf(float f) {
  union { float f; unsigned int i; } c; c.f = f;
  unsigned int lsb = (c.i >> 16) & 1u;
  unsigned int r = c.i + 0x7fffu + lsb;
  return (unsigned short)(r >> 16);
}
__device__ __forceinline__ float softplusf(float v) {
  return v > 0.f ? v + log1pf(expf(-v)) : log1pf(expf(v));
}

// async global -> LDS, 16B per lane; LDS dest is wave-uniform base + lane*16
__device__ __forceinline__ void gload16(const unsigned short* g, unsigned short* l) {
  __builtin_amdgcn_global_load_lds(
      (__attribute__((address_space(1))) unsigned int*)(unsigned long long)g,
      (__attribute__((address_space(3))) unsigned int*)(unsigned int)(unsigned long long)l,
      16, 0, 0);
}

// ---------------- dtype detect ----------------
__global__ void detect_kernel(const unsigned int* __restrict__ dsk) {
  if (threadIdx.x == 0 && blockIdx.x == 0)
    g_isbf16 = (dsk[0] == 0x3F803F80u) ? 1u : 0u;
}

// ---------------- fused convert (8 small/medium weights -> f32 ws) ----------------
__global__ __launch_bounds__(256) void convert_all(
    const void* __restrict__ s0, const void* __restrict__ s1,
    const void* __restrict__ s2, const void* __restrict__ s3,
    const void* __restrict__ s4, const void* __restrict__ s5,
    const void* __restrict__ s6, const void* __restrict__ s7) {
  int i = blockIdx.x * 256 + threadIdx.x;
  if (i >= 7219200) return;
  bool isb = (g_isbf16 != 0u);
  const void* src; unsigned dst; int j;
  if      (i < 6291456) { src = s0; dst = OFF_WEMB; j = i; }
  else if (i < 6316032) { src = s1; dst = OFF_WCW;  j = i - 6291456; }
  else if (i < 6322176) { src = s2; dst = OFF_WCB;  j = i - 6316032; }
  else if (i < 6813696) { src = s3; dst = OFF_WXP;  j = i - 6322176; }
  else if (i < 7108608) { src = s4; dst = OFF_WDW;  j = i - 6813696; }
  else if (i < 7114752) { src = s5; dst = OFF_WDB;  j = i - 7108608; }
  else if (i < 7213056) { src = s6; dst = OFF_WAL;  j = i - 7114752; }
  else                  { src = s7; dst = OFF_WDS;  j = i - 7213056; }
  float v = isb ? bf2f(((const unsigned short*)src)[j]) : ((const float*)src)[j];
  g_ws[dst + j] = v;
}

// ---------------- fused weight hi/lo split ----------------
__global__ __launch_bounds__(256) void splitw_all(
    const void* __restrict__ s0, const void* __restrict__ s1,
    const void* __restrict__ s2, const void* __restrict__ s3) {
  int i = blockIdx.x * 256 + threadIdx.x;
  if (i >= 22806528) return;
  bool isb = (g_isbf16 != 0u);
  const void* src; unsigned hi, lo; int j;
  if      (i <  9437184) { src = s0; hi = BF_IPHI; lo = BF_IPLO; j = i; }
  else if (i < 14155776) { src = s1; hi = BF_OPHI; lo = BF_OPLO; j = i - 9437184; }
  else if (i < 16515072) { src = s2; hi = BF_WUHI; lo = BF_WULO; j = i - 14155776; }
  else                   { src = s3; hi = BF_HWHI; lo = BF_HWLO; j = i - 16515072; }
  float v = isb ? bf2f(((const unsigned short*)src)[j]) : ((const float*)src)[j];
  unsigned short h = f2bf(v);
  g_bf[hi + j] = h;
  g_bf[lo + j] = f2bf(v - bf2f(h));
}

// ---------------- embedding (writes X f32 + hi/lo) ----------------
__global__ __launch_bounds__(256) void embed_kernel(const int* __restrict__ tokens) {
  int t = blockIdx.x;
  int tid = threadIdx.x;
  const float* __restrict__ emb = g_ws + OFF_WEMB;
  int tok[8];
#pragma unroll
  for (int k = 0; k < 8; ++k) tok[k] = tokens[t * 8 + k];
#pragma unroll
  for (int j = 0; j < 3; ++j) {
    int d = tid + j * 256;
    float s = 0.f;
#pragma unroll
    for (int k = 0; k < 8; ++k)
      s += emb[((size_t)k * 1024 + tok[k]) * DMODEL + d];
    size_t idx = (size_t)t * DMODEL + d;
    g_ws[OFF_X + idx] = s;
    unsigned short h = f2bf(s);
    g_bf[BF_XHI + idx] = h;
    g_bf[BF_XLO + idx] = f2bf(s - bf2f(h));
  }
}

// ------- MFMA split-bf16 GEMM body: C[M,N] = A[M,K] * W[N,K]^T -------
// 128(M) x 64(N) tile, BK=32, single-buffer LDS (24KB), 2 barriers/K-step.
// 4 waves, each 32(M) x 64(N): MI=2, NI=4, 24 MFMA per K-step per wave.
// LDS staged in FRAGMENT order (slot l of a 16-row chunk = row (l&15),
// k-slice (l>>4)) -> fragment ds_read_b128 is lane-consecutive,
// bank-conflict-free; the per-lane GLOBAL src realizes the permutation.
// EPI: 0 = store f32 to g_ws; 2 = store to Cout (bf16/f32 per g_isbf16).
template <int EPI>
__device__ __forceinline__ void gemm_body(
    const unsigned short* __restrict__ ahi, const unsigned short* __restrict__ alo,
    const unsigned short* __restrict__ whi, const unsigned short* __restrict__ wlo,
    unsigned coff, void* __restrict__ Cout, int ldc, int K, int bx, int by) {
  __shared__ __align__(16) unsigned short sA[2][128 * 32];  // hi, lo
  __shared__ __align__(16) unsigned short sW[2][64 * 32];
  int tid = threadIdx.x;
  int w = tid >> 6, lane = tid & 63;
  int lm = lane & 15, quad = lane >> 4;
  int bm = by * 128, bn = bx * 64;
  int wr = w * 32;
  int srow = lane & 15;          // fragment-order staging
  int scol = (lane >> 4) * 8;
  int cA = wr >> 4;
  f32x4 acc[2][4] = {};
  for (int k0 = 0; k0 < K; k0 += 32) {
    // 24 chunks of 1 KiB: A-hi 0..7, A-lo 8..15, W-hi 16..19, W-lo 20..23
#pragma unroll
    for (int ci = 0; ci < 6; ++ci) {
      int ch = w + ci * 4;
      const unsigned short* src;
      unsigned short* dst;
      if (ch < 8) {
        src = ahi + (size_t)(bm + ch * 16 + srow) * K + k0 + scol;
        dst = &sA[0][ch * 512];
      } else if (ch < 16) {
        src = alo + (size_t)(bm + (ch - 8) * 16 + srow) * K + k0 + scol;
        dst = &sA[1][(ch - 8) * 512];
      } else if (ch < 20) {
        src = whi + (size_t)(bn + (ch - 16) * 16 + srow) * K + k0 + scol;
        dst = &sW[0][(ch - 16) * 512];
      } else {
        src = wlo + (size_t)(bn + (ch - 20) * 16 + srow) * K + k0 + scol;
        dst = &sW[1][(ch - 20) * 512];
      }
      gload16(src, dst);
    }
    __syncthreads();   // drains vmcnt -> tile landed
    bf16x8 ah[2], al[2], wh[4], wl[4];
#pragma unroll
    for (int mi = 0; mi < 2; ++mi) {
      ah[mi] = *(const bf16x8*)&sA[0][(cA + mi) * 512 + lane * 8];
      al[mi] = *(const bf16x8*)&sA[1][(cA + mi) * 512 + lane * 8];
    }
#pragma unroll
    for (int ni = 0; ni < 4; ++ni) {
      wh[ni] = *(const bf16x8*)&sW[0][ni * 512 + lane * 8];
      wl[ni] = *(const bf16x8*)&sW[1][ni * 512 + lane * 8];
    }
#pragma unroll
    for (int mi = 0; mi < 2; ++mi)
#pragma unroll
      for (int ni = 0; ni < 4; ++ni) {
        acc[mi][ni] = __builtin_amdgcn_mfma_f32_16x16x32_bf16(ah[mi], wh[ni], acc[mi][ni], 0, 0, 0);
        acc[mi][ni] = __builtin_amdgcn_mfma_f32_16x16x32_bf16(ah[mi], wl[ni], acc[mi][ni], 0, 0, 0);
        acc[mi][ni] = __builtin_amdgcn_mfma_f32_16x16x32_bf16(al[mi], wh[ni], acc[mi][ni], 0, 0, 0);
      }
    __syncthreads();   // protect LDS before next stage
  }
  bool outb = (EPI == 2) && (g_isbf16 != 0u);
#pragma unroll
  for (int mi = 0; mi < 2; ++mi)
#pragma unroll
    for (int ni = 0; ni < 4; ++ni)
#pragma unroll
      for (int r = 0; r < 4; ++r) {
        int gm = bm + wr + mi * 16 + quad * 4 + r;
        int gn = bn + ni * 16 + lm;
        float v = acc[mi][ni][r];
        if (EPI == 2) {
          if (outb) ((unsigned short*)Cout)[(size_t)gm * ldc + gn] = f2bf(v);
          else      ((float*)Cout)[(size_t)gm * ldc + gn] = v;
        } else {
          g_ws[coff + (size_t)gm * ldc + gn] = v;
        }
      }
}

template <int EPI>
__global__ __launch_bounds__(256) void gemm_mfma(
    unsigned ahio, unsigned aloo, unsigned whio, unsigned wloo,
    unsigned coff, void* __restrict__ Cout, int ldc, int K) {
  gemm_body<EPI>(g_bf + ahio, g_bf + aloo, g_bf + whio, g_bf + wloo,
                 coff, Cout, ldc, K, blockIdx.x, blockIdx.y);
}

// fused out_proj (z=0) + W_u (z=1): both 2048 x 768
__global__ __launch_bounds__(256) void gemm_mid(
    unsigned ophi, unsigned oplo, unsigned wuhi, unsigned wulo) {
  if (blockIdx.z == 0) {
    gemm_body<0>(g_bf + BF_YHI, g_bf + BF_YLO, g_bf + ophi, g_bf + oplo,
                 OFF_XOUT, nullptr, DMODEL, DIN, blockIdx.x, blockIdx.y);
  } else {
    gemm_body<0>(g_bf + BF_XHI, g_bf + BF_XLO, g_bf + wuhi, g_bf + wulo,
                 OFF_URET, nullptr, DMODEL, DMODEL, blockIdx.x, blockIdx.y);
  }
}

// ------- small f32 NT GEMM (kept for dbc / dt) -------
template <int EPI>
__global__ __launch_bounds__(256) void gemm_nt(
    unsigned int aoff, int lda, unsigned int boff, int ldb,
    unsigned int coff, int ldc, int M, int N, int K, unsigned int biasoff) {
  const float* __restrict__ A = g_ws + aoff;
  const float* __restrict__ Bw = g_ws + boff;
  __shared__ float As[16][68];
  __shared__ float Bs[16][68];
  int tid = threadIdx.x;
  int bx = blockIdx.x, by = blockIdx.y;
  int tx = tid & 15, ty = tid >> 4;
  int lr = tid >> 2;
  int lc = (tid & 3) * 4;
  float acc[4][4] = {};
  for (int k0 = 0; k0 < K; k0 += 16) {
    const float* ap = A + (size_t)(by * 64 + lr) * lda + k0 + lc;
    float4 av = *reinterpret_cast<const float4*>(ap);
    As[lc + 0][lr] = av.x; As[lc + 1][lr] = av.y;
    As[lc + 2][lr] = av.z; As[lc + 3][lr] = av.w;
    int bn = bx * 64 + lr;
    float4 bv = make_float4(0.f, 0.f, 0.f, 0.f);
    if (bn < N)
      bv = *reinterpret_cast<const float4*>(Bw + (size_t)bn * ldb + k0 + lc);
    Bs[lc + 0][lr] = bv.x; Bs[lc + 1][lr] = bv.y;
    Bs[lc + 2][lr] = bv.z; Bs[lc + 3][lr] = bv.w;
    __syncthreads();
#pragma unroll
    for (int kk = 0; kk < 16; ++kk) {
      float4 a = *reinterpret_cast<const float4*>(&As[kk][ty * 4]);
      float4 b = *reinterpret_cast<const float4*>(&Bs[kk][tx * 4]);
      float ar[4] = {a.x, a.y, a.z, a.w};
      float br[4] = {b.x, b.y, b.z, b.w};
#pragma unroll
      for (int i = 0; i < 4; ++i)
#pragma unroll
        for (int j = 0; j < 4; ++j) acc[i][j] = fmaf(ar[i], br[j], acc[i][j]);
    }
    __syncthreads();
  }
  int m0 = by * 64 + ty * 4, n0 = bx * 64 + tx * 4;
#pragma unroll
  for (int i = 0; i < 4; ++i) {
#pragma unroll
    for (int j = 0; j < 4; ++j) {
      int m = m0 + i, n = n0 + j;
      if (n < N) {
        float v = acc[i][j];
        if (EPI == 1) v = softplusf(v + g_ws[biasoff + n]);
        g_ws[coff + (size_t)m * ldc + n] = v;
      }
    }
  }
}

// ---------------- depthwise causal conv(4) + SiLU ----------------
__global__ __launch_bounds__(256) void conv_silu_kernel(
    unsigned int cwoff, unsigned int cboff) {
  int idx = blockIdx.x * 256 + threadIdx.x;
  int t = idx / DIN, e = idx - t * DIN;
  const float* __restrict__ xz = g_ws + OFF_XZ;
  const float* __restrict__ cw = g_ws + cwoff;
  float w0 = cw[e * 4 + 0], w1 = cw[e * 4 + 1];
  float w2 = cw[e * 4 + 2], w3 = cw[e * 4 + 3];
  float acc = g_ws[cboff + e];
  if (t >= 3) acc = fmaf(w0, xz[(size_t)(t - 3) * DXZ + e], acc);
  if (t >= 2) acc = fmaf(w1, xz[(size_t)(t - 2) * DXZ + e], acc);
  if (t >= 1) acc = fmaf(w2, xz[(size_t)(t - 1) * DXZ + e], acc);
  acc = fmaf(w3, xz[(size_t)t * DXZ + e], acc);
  float sig = 1.f / (1.f + __expf(-acc));
  g_ws[OFF_UC + idx] = acc * sig;
}

// ------- chunked selective scan -------
__global__ __launch_bounds__(256) void scan_phase1(unsigned int aloff) {
  int tid = threadIdx.x;
  int s = tid & 15;
  int e = blockIdx.x * 16 + (tid >> 4);
  int c = blockIdx.y;
  int t0 = c * CH;
  const float* __restrict__ delta = g_ws + OFF_DELTA;
  const float* __restrict__ uc    = g_ws + OFF_UC;
  const float* __restrict__ dbc   = g_ws + OFF_DBC;
  float a = -expf(g_ws[aloff + e * NSTATE + s]);
  float h = 0.f, P = 0.f;
  for (int i = 0; i < CH; ++i) {
    int t = t0 + i;
    float d = delta[(size_t)t * DIN + e];
    float u = uc[(size_t)t * DIN + e];
    float b = dbc[t * FDIM + DTRANK + s];
    float cc = dbc[t * FDIM + DTRANK + NSTATE + s];
    float dA = __expf(d * a);
    h = fmaf(dA, h, d * u * b);
    P += d;
    float yp = h * cc;
    yp += __shfl_xor(yp, 1);
    yp += __shfl_xor(yp, 2);
    yp += __shfl_xor(yp, 4);
    yp += __shfl_xor(yp, 8);
    if (s == 0) g_ws[OFF_Y + (size_t)t * DIN + e] = yp;
  }
  g_ws[OFF_SLOC + ((size_t)c * DIN + e) * NSTATE + s] = h;
  if (s == 0) g_ws[OFF_CHP + c * DIN + e] = P;
}

__global__ __launch_bounds__(256) void scan_phase2(unsigned int aloff) {
  int g = blockIdx.x * 256 + threadIdx.x;
  int e = g >> 4, s = g & 15;
  float a = -expf(g_ws[aloff + e * NSTATE + s]);
  float h = 0.f;
  for (int c = 0; c < NC; ++c) {
    g_ws[OFF_HIN + ((size_t)c * DIN + e) * NSTATE + s] = h;
    float S = g_ws[OFF_SLOC + ((size_t)c * DIN + e) * NSTATE + s];
    float P = g_ws[OFF_CHP + c * DIN + e];
    h = fmaf(__expf(a * P), h, S);
  }
}

// phase3 writes final y directly as bf16 hi/lo (consumed only by out_proj)
__global__ __launch_bounds__(256) void scan_phase3(unsigned int aloff,
                                                   unsigned int dsoff) {
  int tid = threadIdx.x;
  int s = tid & 15;
  int e = blockIdx.x * 16 + (tid >> 4);
  int c = blockIdx.y;
  int t0 = c * CH;
  const float* __restrict__ delta = g_ws + OFF_DELTA;
  const float* __restrict__ uc    = g_ws + OFF_UC;
  const float* __restrict__ dbc   = g_ws + OFF_DBC;
  const float* __restrict__ xz    = g_ws + OFF_XZ;
  float a = -expf(g_ws[aloff + e * NSTATE + s]);
  float dsk = g_ws[dsoff + e];
  float hin = g_ws[OFF_HIN + ((size_t)c * DIN + e) * NSTATE + s];
  float P = 0.f;
  for (int i = 0; i < CH; ++i) {
    int t = t0 + i;
    float d = delta[(size_t)t * DIN + e];
    P += d;
    float cc = dbc[t * FDIM + DTRANK + NSTATE + s];
    float yp = __expf(a * P) * hin * cc;
    yp += __shfl_xor(yp, 1);
    yp += __shfl_xor(yp, 2);
    yp += __shfl_xor(yp, 4);
    yp += __shfl_xor(yp, 8);
    if (s == 0) {
      float u = uc[(size_t)t * DIN + e];
      float z = xz[(size_t)t * DXZ + DIN + e];
      float y = g_ws[OFF_Y + (size_t)t * DIN + e] + yp;
      float sig = 1.f / (1.f + __expf(-z));
      float v = (y + dsk * u) * z * sig;
      size_t idx = (size_t)t * DIN + e;
      unsigned short h = f2bf(v);
      g_bf[BF_YHI + idx] = h;
      g_bf[BF_YLO + idx] = f2bf(v - bf2f(h));
    }
  }
}

// ---------------- running segment mean (m_current) ----------------
// Also supplies m_stack: m_stack[n][d] == mcur[(n+1)*SEG-1][d] bit-exactly.
__global__ __launch_bounds__(256) void mcurrent_kernel() {
  int n = blockIdx.x / 3;
  int d = (blockIdx.x % 3) * 256 + threadIdx.x;
  const float* __restrict__ x = g_ws + OFF_X + (size_t)n * SEGLEN * DMODEL + d;
  float* __restrict__ mc = g_ws + OFF_MCUR + (size_t)n * SEGLEN * DMODEL + d;
  float run = 0.f;
  for (int i = 0; i < SEGLEN; ++i) {
    run += x[(size_t)i * DMODEL];
    mc[(size_t)i * DMODEL] = run / (float)(i + 1);
  }
}

// ---------------- retention (writes X f32 + hi/lo) ----------------
__global__ __launch_bounds__(256) void retention_kernel() {
  int t = blockIdx.x;
  int tid = threadIdx.x;
  const float* __restrict__ xout = g_ws + OFF_XOUT;
  const float* __restrict__ uret = g_ws + OFF_URET;
  const float* __restrict__ mcur = g_ws + OFF_MCUR;
  __shared__ float red[4][9];
  __shared__ float attn_s[9];
  float p[9];
#pragma unroll
  for (int n = 0; n < 9; ++n) p[n] = 0.f;
#pragma unroll
  for (int j = 0; j < 3; ++j) {
    int d = tid + j * 256;
    float u = uret[(size_t)t * DMODEL + d];
    p[8] = fmaf(u, mcur[(size_t)t * DMODEL + d], p[8]);
#pragma unroll
    for (int n = 0; n < 8; ++n)
      p[n] = fmaf(u, mcur[(size_t)(n * SEGLEN + SEGLEN - 1) * DMODEL + d], p[n]);
  }
#pragma unroll
  for (int off = 32; off > 0; off >>= 1)
#pragma unroll
    for (int n = 0; n < 9; ++n) p[n] += __shfl_down(p[n], off, 64);
  int wave = tid >> 6;
  if ((tid & 63) == 0)
#pragma unroll
    for (int n = 0; n < 9; ++n) red[wave][n] = p[n];
  __syncthreads();
  if (tid == 0) {
    const float scale = 0.03608439182435161f;
    int seg = t >> 8;
    float sc[9], mx = -3.0e38f;
#pragma unroll
    for (int n = 0; n < 9; ++n) {
      float v = (red[0][n] + red[1][n] + red[2][n] + red[3][n]) * scale;
      if (n < 8 && n >= seg) v = -1e30f;
      sc[n] = v;
      mx = fmaxf(mx, v);
    }
    float den = 0.f;
#pragma unroll
    for (int n = 0; n < 9; ++n) {
      float e = __expf(sc[n] - mx);
      sc[n] = e;
      den += e;
    }
    float inv = 1.f / den;
#pragma unroll
    for (int n = 0; n < 9; ++n) attn_s[n] = sc[n] * inv;
  }
  __syncthreads();
  float a[9];
#pragma unroll
  for (int n = 0; n < 9; ++n) a[n] = attn_s[n];
#pragma unroll
  for (int j = 0; j < 3; ++j) {
    int d = tid + j * 256;
    float acc = a[8] * xout[(size_t)t * DMODEL + d];
#pragma unroll
    for (int n = 0; n < 8; ++n)
      acc = fmaf(a[n], xout[(size_t)(n * SEGLEN + SEGLEN - 1) * DMODEL + d], acc);
    size_t idx = (size_t)t * DMODEL + d;
    g_ws[OFF_X + idx] = acc;
    unsigned short h = f2bf(acc);
    g_bf[BF_XHI + idx] = h;
    g_bf[BF_XLO + idx] = f2bf(acc - bf2f(h));
  }
}

extern "C" void kernel_launch(void* const* d_in, const int* in_sizes, int n_in,
                              void* d_out, int out_size, void* d_ws, size_t ws_size,
                              hipStream_t stream) {
  (void)in_sizes; (void)n_in; (void)out_size; (void)d_ws; (void)ws_size;
  const int* tokens = (const int*)d_in[0];

  detect_kernel<<<1, 64, 0, stream>>>((const unsigned int*)d_in[10]);

  convert_all<<<(7219200 + 255) / 256, 256, 0, stream>>>(
      d_in[1], d_in[4], d_in[5], d_in[6], d_in[7], d_in[8], d_in[9], d_in[10]);
  splitw_all<<<(22806528 + 255) / 256, 256, 0, stream>>>(
      d_in[3], d_in[11], d_in[2], d_in[12]);

  embed_kernel<<<T_LEN, 256, 0, stream>>>(tokens);

  for (int l = 0; l < 4; ++l) {
    unsigned int xp = OFF_WXP + (unsigned)l * FDIM * DIN;
    unsigned int dw = OFF_WDW + (unsigned)l * DIN * DTRANK;
    unsigned int db = OFF_WDB + (unsigned)l * DIN;
    unsigned int al = OFF_WAL + (unsigned)l * DIN * NSTATE;
    unsigned int ds = OFF_WDS + (unsigned)l * DIN;
    unsigned int cw = OFF_WCW + (unsigned)l * DIN * 4;
    unsigned int cb = OFF_WCB + (unsigned)l * DIN;
    unsigned int iphi = BF_IPHI + (unsigned)l * DXZ * DMODEL;
    unsigned int iplo = BF_IPLO + (unsigned)l * DXZ * DMODEL;
    unsigned int ophi = BF_OPHI + (unsigned)l * DMODEL * DIN;
    unsigned int oplo = BF_OPLO + (unsigned)l * DMODEL * DIN;
    unsigned int wuhi = BF_WUHI + (unsigned)l * DMODEL * DMODEL;
    unsigned int wulo = BF_WULO + (unsigned)l * DMODEL * DMODEL;

    // xz = x @ in_proj^T   (2048 x 3072, K=768), 48x16 = 768 blocks
    gemm_mfma<0><<<dim3(DXZ / 64, T_LEN / 128), 256, 0, stream>>>(
        BF_XHI, BF_XLO, iphi, iplo, OFF_XZ, nullptr, DXZ, DMODEL);
    conv_silu_kernel<<<(T_LEN * DIN) / 256, 256, 0, stream>>>(cw, cb);
    // dbc = uc @ x_proj^T  (2048 x 80, K=1536)
    gemm_nt<0><<<dim3(2, 32), 256, 0, stream>>>(OFF_UC, DIN, xp, DIN,
                                                OFF_DBC, FDIM, T_LEN, FDIM, DIN, 0u);
    // delta = softplus(dbc[:, :48] @ dt_w^T + dt_b)
    gemm_nt<1><<<dim3(24, 32), 256, 0, stream>>>(OFF_DBC, FDIM, dw, DTRANK,
                                                 OFF_DELTA, DIN, T_LEN, DIN, DTRANK, db);
    // chunked selective scan (phase3 emits y hi/lo directly)
    scan_phase1<<<dim3(DIN / 16, NC), 256, 0, stream>>>(al);
    scan_phase2<<<(DIN * NSTATE) / 256, 256, 0, stream>>>(al);
    scan_phase3<<<dim3(DIN / 16, NC), 256, 0, stream>>>(al, ds);
    // m_current (independent of GEMMs), then fused out_proj + W_u
    mcurrent_kernel<<<NSEG * 3, 256, 0, stream>>>();
    gemm_mid<<<dim3(DMODEL / 64, T_LEN / 128, 2), 256, 0, stream>>>(
        ophi, oplo, wuhi, wulo);
    // retention emits next-layer x hi/lo directly
    retention_kernel<<<T_LEN, 256, 0, stream>>>();
  }

  // logits = x @ head_w^T  (2048 x 8192, K=768), 128x16 = 2048 blocks
  gemm_mfma<2><<<dim3(NHEADV / 64, T_LEN / 128), 256, 0, stream>>>(
      BF_XHI, BF_XLO, BF_HWHI, BF_HWLO, 0u, d_out, NHEADV, DMODEL);
}

// Round 6
// 2350.448 us; speedup vs baseline: 1.0419x; 1.0419x over previous
//
#include <hip/hip_runtime.h>
#include <hip/hip_bf16.h>

// MCMambaLM: B=1, T=2048, D=768, K=8, V=1024, D_IN=1536, D_STATE=16,
// D_CONV=4, DT_RANK=48, L=4, SEG=256, n_seg=8.
// Round 11: BN=128 tiles for in_proj/head (higher arithmetic intensity wins
// over BN=64 occupancy: fewer K-step drains + fewer staged bytes), fragment-
// order conflict-free staging, single-buffer 32KB LDS, NO xcd swizzle
// (natural round-robin keeps per-XCD W panels L2-resident). Mid GEMMs BN=64
// fused z=2. Producer-fused hi/lo splits kept.

#define T_LEN   2048
#define DMODEL  768
#define DIN     1536
#define DXZ     3072
#define NSTATE  16
#define DTRANK  48
#define FDIM    80
#define NSEG    8
#define SEGLEN  256
#define NHEADV  8192
#define CH      64
#define NC      32

// ---- f32 scratch ----
#define OFF_X     0u
#define OFF_XZ    1572864u
#define OFF_UC    7864320u
#define OFF_DBC   11010048u
#define OFF_DELTA 11173888u
#define OFF_Y     14319616u
#define OFF_XOUT  17465344u
#define OFF_URET  19038208u
#define OFF_MCUR  20611072u
#define OFF_MSTK  22183936u
#define OFF_WEMB  22190080u   // 8*1024*768
#define OFF_WCW   28481536u   // 4*1536*4
#define OFF_WCB   28506112u   // 4*1536
#define OFF_WXP   28512256u   // 4*80*1536
#define OFF_WDW   29003776u   // 4*1536*48
#define OFF_WDB   29298688u   // 4*1536
#define OFF_WAL   29304832u   // 4*1536*16
#define OFF_WDS   29403136u   // 4*1536
#define OFF_SLOC  29409280u   // NC*DIN*16
#define OFF_HIN   30195712u
#define OFF_CHP   30982144u   // NC*DIN
#define WS_TOTAL  31031296u
__device__ __align__(16) float g_ws[WS_TOTAL];

// ---- bf16 hi/lo scratch (ushort elems) ----
#define BF_XHI   0u          // 2048*768
#define BF_XLO   1572864u
#define BF_YHI   3145728u    // 2048*1536
#define BF_YLO   6291456u
#define BF_IPHI  9437184u    // 4*3072*768
#define BF_IPLO  18874368u
#define BF_OPHI  28311552u   // 4*768*1536
#define BF_OPLO  33030144u
#define BF_WUHI  37748736u   // 4*768*768
#define BF_WULO  40108032u
#define BF_HWHI  42467328u   // 8192*768
#define BF_HWLO  48758784u
#define BF_TOTAL 55050240u
__device__ __align__(16) unsigned short g_bf[BF_TOTAL];
__device__ unsigned int g_isbf16;

typedef __attribute__((ext_vector_type(8))) short bf16x8;
typedef __attribute__((ext_vector_type(4))) float f32x4;

__device__ __forceinline__ float bf2f(unsigned short u) {
  union { unsigned int i; float f; } c; c.i = ((unsigned int)u) << 16; return c.f;
}
__device__ __forceinline__ unsigned short f2bf(float f) {
  union { float f; unsigned int i; } c; c.f = f;
  unsigned int lsb = (c.i >> 16) & 1u;
  unsigned int r = c.i + 0x7fffu + lsb;
  return (unsigned short)(r >> 16);
}
__device__ __forceinline__ float softplusf(float v) {
  return v > 0.f ? v + log1pf(expf(-v)) : log1pf(expf(v));
}

// async global -> LDS, 16B per lane; LDS dest is wave-uniform base + lane*16
__device__ __forceinline__ void gload16(const unsigned short* g, unsigned short* l) {
  __builtin_amdgcn_global_load_lds(
      (__attribute__((address_space(1))) unsigned int*)(unsigned long long)g,
      (__attribute__((address_space(3))) unsigned int*)(unsigned int)(unsigned long long)l,
      16, 0, 0);
}

// ---------------- dtype detect ----------------
__global__ void detect_kernel(const unsigned int* __restrict__ dsk) {
  if (threadIdx.x == 0 && blockIdx.x == 0)
    g_isbf16 = (dsk[0] == 0x3F803F80u) ? 1u : 0u;
}

// ---------------- fused convert (8 small/medium weights -> f32 ws) ----------------
__global__ __launch_bounds__(256) void convert_all(
    const void* __restrict__ s0, const void* __restrict__ s1,
    const void* __restrict__ s2, const void* __restrict__ s3,
    const void* __restrict__ s4, const void* __restrict__ s5,
    const void* __restrict__ s6, const void* __restrict__ s7) {
  int i = blockIdx.x * 256 + threadIdx.x;
  if (i >= 7219200) return;
  bool isb = (g_isbf16 != 0u);
  const void* src; unsigned dst; int j;
  if      (i < 6291456) { src = s0; dst = OFF_WEMB; j = i; }
  else if (i < 6316032) { src = s1; dst = OFF_WCW;  j = i - 6291456; }
  else if (i < 6322176) { src = s2; dst = OFF_WCB;  j = i - 6316032; }
  else if (i < 6813696) { src = s3; dst = OFF_WXP;  j = i - 6322176; }
  else if (i < 7108608) { src = s4; dst = OFF_WDW;  j = i - 6813696; }
  else if (i < 7114752) { src = s5; dst = OFF_WDB;  j = i - 7108608; }
  else if (i < 7213056) { src = s6; dst = OFF_WAL;  j = i - 7114752; }
  else                  { src = s7; dst = OFF_WDS;  j = i - 7213056; }
  float v = isb ? bf2f(((const unsigned short*)src)[j]) : ((const float*)src)[j];
  g_ws[dst + j] = v;
}

// ---------------- fused weight hi/lo split ----------------
__global__ __launch_bounds__(256) void splitw_all(
    const void* __restrict__ s0, const void* __restrict__ s1,
    const void* __restrict__ s2, const void* __restrict__ s3) {
  int i = blockIdx.x * 256 + threadIdx.x;
  if (i >= 22806528) return;
  bool isb = (g_isbf16 != 0u);
  const void* src; unsigned hi, lo; int j;
  if      (i <  9437184) { src = s0; hi = BF_IPHI; lo = BF_IPLO; j = i; }
  else if (i < 14155776) { src = s1; hi = BF_OPHI; lo = BF_OPLO; j = i - 9437184; }
  else if (i < 16515072) { src = s2; hi = BF_WUHI; lo = BF_WULO; j = i - 14155776; }
  else                   { src = s3; hi = BF_HWHI; lo = BF_HWLO; j = i - 16515072; }
  float v = isb ? bf2f(((const unsigned short*)src)[j]) : ((const float*)src)[j];
  unsigned short h = f2bf(v);
  g_bf[hi + j] = h;
  g_bf[lo + j] = f2bf(v - bf2f(h));
}

// ---------------- embedding (writes X f32 + hi/lo) ----------------
__global__ __launch_bounds__(256) void embed_kernel(const int* __restrict__ tokens) {
  int t = blockIdx.x;
  int tid = threadIdx.x;
  const float* __restrict__ emb = g_ws + OFF_WEMB;
  int tok[8];
#pragma unroll
  for (int k = 0; k < 8; ++k) tok[k] = tokens[t * 8 + k];
#pragma unroll
  for (int j = 0; j < 3; ++j) {
    int d = tid + j * 256;
    float s = 0.f;
#pragma unroll
    for (int k = 0; k < 8; ++k)
      s += emb[((size_t)k * 1024 + tok[k]) * DMODEL + d];
    size_t idx = (size_t)t * DMODEL + d;
    g_ws[OFF_X + idx] = s;
    unsigned short h = f2bf(s);
    g_bf[BF_XHI + idx] = h;
    g_bf[BF_XLO + idx] = f2bf(s - bf2f(h));
  }
}

// ------- MFMA split-bf16 GEMM body: C[M,N] = A[M,K] * W[N,K]^T -------
// 128(M) x BN(N) tile, BK=32, single-buffer LDS, 2 barriers/K-step.
// 4 waves. BN=128: 2x2 wave grid (64x64/wave, 48 MFMA/K-step); BN=64:
// 4x1 wave grid (32x64/wave, 24 MFMA/K-step).
// LDS staged in FRAGMENT order (slot l of a 16-row chunk = row (l&15),
// k-slice (l>>4)) -> fragment ds_read_b128 is lane-consecutive,
// bank-conflict-free; the per-lane GLOBAL src realizes the permutation.
// EPI: 0 = store f32 to g_ws; 2 = store to Cout (bf16/f32 per g_isbf16).
template <int BN, int EPI>
__device__ __forceinline__ void gemm_body(
    const unsigned short* __restrict__ ahi, const unsigned short* __restrict__ alo,
    const unsigned short* __restrict__ whi, const unsigned short* __restrict__ wlo,
    unsigned coff, void* __restrict__ Cout, int ldc, int K, int bx, int by) {
  constexpr int NWH = BN / 16;        // W 16-row chunks per (hi|lo) half
  constexpr int NCH = 16 + 2 * NWH;   // total 1 KiB chunks per K-step
  constexpr int MI  = (BN == 128) ? 4 : 2;
  __shared__ __align__(16) unsigned short sA[2][128 * 32];  // hi, lo
  __shared__ __align__(16) unsigned short sW[2][BN * 32];
  int tid = threadIdx.x;
  int w = tid >> 6, lane = tid & 63;
  int lm = lane & 15, quad = lane >> 4;
  int bm = by * 128, bn = bx * BN;
  int wr = (BN == 128) ? ((w >> 1) * 64) : (w * 32);
  int wc = (BN == 128) ? ((w & 1) * 64) : 0;
  int srow = lane & 15;          // fragment-order staging
  int scol = (lane >> 4) * 8;
  int cA = wr >> 4, cW = wc >> 4;
  f32x4 acc[MI][4] = {};
  for (int k0 = 0; k0 < K; k0 += 32) {
#pragma unroll
    for (int ci = 0; ci < NCH / 4; ++ci) {
      int ch = w + ci * 4;
      const unsigned short* src;
      unsigned short* dst;
      if (ch < 8) {
        src = ahi + (size_t)(bm + ch * 16 + srow) * K + k0 + scol;
        dst = &sA[0][ch * 512];
      } else if (ch < 16) {
        src = alo + (size_t)(bm + (ch - 8) * 16 + srow) * K + k0 + scol;
        dst = &sA[1][(ch - 8) * 512];
      } else if (ch < 16 + NWH) {
        src = whi + (size_t)(bn + (ch - 16) * 16 + srow) * K + k0 + scol;
        dst = &sW[0][(ch - 16) * 512];
      } else {
        src = wlo + (size_t)(bn + (ch - 16 - NWH) * 16 + srow) * K + k0 + scol;
        dst = &sW[1][(ch - 16 - NWH) * 512];
      }
      gload16(src, dst);
    }
    __syncthreads();   // drains vmcnt -> tile landed
    bf16x8 ah[MI], al[MI], wh[4], wl[4];
#pragma unroll
    for (int mi = 0; mi < MI; ++mi) {
      ah[mi] = *(const bf16x8*)&sA[0][(cA + mi) * 512 + lane * 8];
      al[mi] = *(const bf16x8*)&sA[1][(cA + mi) * 512 + lane * 8];
    }
#pragma unroll
    for (int ni = 0; ni < 4; ++ni) {
      wh[ni] = *(const bf16x8*)&sW[0][(cW + ni) * 512 + lane * 8];
      wl[ni] = *(const bf16x8*)&sW[1][(cW + ni) * 512 + lane * 8];
    }
#pragma unroll
    for (int mi = 0; mi < MI; ++mi)
#pragma unroll
      for (int ni = 0; ni < 4; ++ni) {
        acc[mi][ni] = __builtin_amdgcn_mfma_f32_16x16x32_bf16(ah[mi], wh[ni], acc[mi][ni], 0, 0, 0);
        acc[mi][ni] = __builtin_amdgcn_mfma_f32_16x16x32_bf16(ah[mi], wl[ni], acc[mi][ni], 0, 0, 0);
        acc[mi][ni] = __builtin_amdgcn_mfma_f32_16x16x32_bf16(al[mi], wh[ni], acc[mi][ni], 0, 0, 0);
      }
    __syncthreads();   // protect LDS before next stage
  }
  bool outb = (EPI == 2) && (g_isbf16 != 0u);
#pragma unroll
  for (int mi = 0; mi < MI; ++mi)
#pragma unroll
    for (int ni = 0; ni < 4; ++ni)
#pragma unroll
      for (int r = 0; r < 4; ++r) {
        int gm = bm + wr + mi * 16 + quad * 4 + r;
        int gn = bn + wc + ni * 16 + lm;
        float v = acc[mi][ni][r];
        if (EPI == 2) {
          if (outb) ((unsigned short*)Cout)[(size_t)gm * ldc + gn] = f2bf(v);
          else      ((float*)Cout)[(size_t)gm * ldc + gn] = v;
        } else {
          g_ws[coff + (size_t)gm * ldc + gn] = v;
        }
      }
}

template <int BN, int EPI>
__global__ __launch_bounds__(256) void gemm_mfma(
    unsigned ahio, unsigned aloo, unsigned whio, unsigned wloo,
    unsigned coff, void* __restrict__ Cout, int ldc, int K) {
  gemm_body<BN, EPI>(g_bf + ahio, g_bf + aloo, g_bf + whio, g_bf + wloo,
                     coff, Cout, ldc, K, blockIdx.x, blockIdx.y);
}

// fused out_proj (z=0) + W_u (z=1): both 2048 x 768, BN=64
__global__ __launch_bounds__(256) void gemm_mid(
    unsigned ophi, unsigned oplo, unsigned wuhi, unsigned wulo) {
  if (blockIdx.z == 0) {
    gemm_body<64, 0>(g_bf + BF_YHI, g_bf + BF_YLO, g_bf + ophi, g_bf + oplo,
                     OFF_XOUT, nullptr, DMODEL, DIN, blockIdx.x, blockIdx.y);
  } else {
    gemm_body<64, 0>(g_bf + BF_XHI, g_bf + BF_XLO, g_bf + wuhi, g_bf + wulo,
                     OFF_URET, nullptr, DMODEL, DMODEL, blockIdx.x, blockIdx.y);
  }
}

// ------- small f32 NT GEMM (kept for dbc / dt) -------
template <int EPI>
__global__ __launch_bounds__(256) void gemm_nt(
    unsigned int aoff, int lda, unsigned int boff, int ldb,
    unsigned int coff, int ldc, int M, int N, int K, unsigned int biasoff) {
  const float* __restrict__ A = g_ws + aoff;
  const float* __restrict__ Bw = g_ws + boff;
  __shared__ float As[16][68];
  __shared__ float Bs[16][68];
  int tid = threadIdx.x;
  int bx = blockIdx.x, by = blockIdx.y;
  int tx = tid & 15, ty = tid >> 4;
  int lr = tid >> 2;
  int lc = (tid & 3) * 4;
  float acc[4][4] = {};
  for (int k0 = 0; k0 < K; k0 += 16) {
    const float* ap = A + (size_t)(by * 64 + lr) * lda + k0 + lc;
    float4 av = *reinterpret_cast<const float4*>(ap);
    As[lc + 0][lr] = av.x; As[lc + 1][lr] = av.y;
    As[lc + 2][lr] = av.z; As[lc + 3][lr] = av.w;
    int bn = bx * 64 + lr;
    float4 bv = make_float4(0.f, 0.f, 0.f, 0.f);
    if (bn < N)
      bv = *reinterpret_cast<const float4*>(Bw + (size_t)bn * ldb + k0 + lc);
    Bs[lc + 0][lr] = bv.x; Bs[lc + 1][lr] = bv.y;
    Bs[lc + 2][lr] = bv.z; Bs[lc + 3][lr] = bv.w;
    __syncthreads();
#pragma unroll
    for (int kk = 0; kk < 16; ++kk) {
      float4 a = *reinterpret_cast<const float4*>(&As[kk][ty * 4]);
      float4 b = *reinterpret_cast<const float4*>(&Bs[kk][tx * 4]);
      float ar[4] = {a.x, a.y, a.z, a.w};
      float br[4] = {b.x, b.y, b.z, b.w};
#pragma unroll
      for (int i = 0; i < 4; ++i)
#pragma unroll
        for (int j = 0; j < 4; ++j) acc[i][j] = fmaf(ar[i], br[j], acc[i][j]);
    }
    __syncthreads();
  }
  int m0 = by * 64 + ty * 4, n0 = bx * 64 + tx * 4;
#pragma unroll
  for (int i = 0; i < 4; ++i) {
#pragma unroll
    for (int j = 0; j < 4; ++j) {
      int m = m0 + i, n = n0 + j;
      if (n < N) {
        float v = acc[i][j];
        if (EPI == 1) v = softplusf(v + g_ws[biasoff + n]);
        g_ws[coff + (size_t)m * ldc + n] = v;
      }
    }
  }
}

// ---------------- depthwise causal conv(4) + SiLU ----------------
__global__ __launch_bounds__(256) void conv_silu_kernel(
    unsigned int cwoff, unsigned int cboff) {
  int idx = blockIdx.x * 256 + threadIdx.x;
  int t = idx / DIN, e = idx - t * DIN;
  const float* __restrict__ xz = g_ws + OFF_XZ;
  const float* __restrict__ cw = g_ws + cwoff;
  float w0 = cw[e * 4 + 0], w1 = cw[e * 4 + 1];
  float w2 = cw[e * 4 + 2], w3 = cw[e * 4 + 3];
  float acc = g_ws[cboff + e];
  if (t >= 3) acc = fmaf(w0, xz[(size_t)(t - 3) * DXZ + e], acc);
  if (t >= 2) acc = fmaf(w1, xz[(size_t)(t - 2) * DXZ + e], acc);
  if (t >= 1) acc = fmaf(w2, xz[(size_t)(t - 1) * DXZ + e], acc);
  acc = fmaf(w3, xz[(size_t)t * DXZ + e], acc);
  float sig = 1.f / (1.f + __expf(-acc));
  g_ws[OFF_UC + idx] = acc * sig;
}

// ------- chunked selective scan -------
__global__ __launch_bounds__(256) void scan_phase1(unsigned int aloff) {
  int tid = threadIdx.x;
  int s = tid & 15;
  int e = blockIdx.x * 16 + (tid >> 4);
  int c = blockIdx.y;
  int t0 = c * CH;
  const float* __restrict__ delta = g_ws + OFF_DELTA;
  const float* __restrict__ uc    = g_ws + OFF_UC;
  const float* __restrict__ dbc   = g_ws + OFF_DBC;
  float a = -expf(g_ws[aloff + e * NSTATE + s]);
  float h = 0.f, P = 0.f;
  for (int i = 0; i < CH; ++i) {
    int t = t0 + i;
    float d = delta[(size_t)t * DIN + e];
    float u = uc[(size_t)t * DIN + e];
    float b = dbc[t * FDIM + DTRANK + s];
    float cc = dbc[t * FDIM + DTRANK + NSTATE + s];
    float dA = __expf(d * a);
    h = fmaf(dA, h, d * u * b);
    P += d;
    float yp = h * cc;
    yp += __shfl_xor(yp, 1);
    yp += __shfl_xor(yp, 2);
    yp += __shfl_xor(yp, 4);
    yp += __shfl_xor(yp, 8);
    if (s == 0) g_ws[OFF_Y + (size_t)t * DIN + e] = yp;
  }
  g_ws[OFF_SLOC + ((size_t)c * DIN + e) * NSTATE + s] = h;
  if (s == 0) g_ws[OFF_CHP + c * DIN + e] = P;
}

__global__ __launch_bounds__(256) void scan_phase2(unsigned int aloff) {
  int g = blockIdx.x * 256 + threadIdx.x;
  int e = g >> 4, s = g & 15;
  float a = -expf(g_ws[aloff + e * NSTATE + s]);
  float h = 0.f;
  for (int c = 0; c < NC; ++c) {
    g_ws[OFF_HIN + ((size_t)c * DIN + e) * NSTATE + s] = h;
    float S = g_ws[OFF_SLOC + ((size_t)c * DIN + e) * NSTATE + s];
    float P = g_ws[OFF_CHP + c * DIN + e];
    h = fmaf(__expf(a * P), h, S);
  }
}

// phase3 writes final y directly as bf16 hi/lo (consumed only by out_proj)
__global__ __launch_bounds__(256) void scan_phase3(unsigned int aloff,
                                                   unsigned int dsoff) {
  int tid = threadIdx.x;
  int s = tid & 15;
  int e = blockIdx.x * 16 + (tid >> 4);
  int c = blockIdx.y;
  int t0 = c * CH;
  const float* __restrict__ delta = g_ws + OFF_DELTA;
  const float* __restrict__ uc    = g_ws + OFF_UC;
  const float* __restrict__ dbc   = g_ws + OFF_DBC;
  const float* __restrict__ xz    = g_ws + OFF_XZ;
  float a = -expf(g_ws[aloff + e * NSTATE + s]);
  float dsk = g_ws[dsoff + e];
  float hin = g_ws[OFF_HIN + ((size_t)c * DIN + e) * NSTATE + s];
  float P = 0.f;
  for (int i = 0; i < CH; ++i) {
    int t = t0 + i;
    float d = delta[(size_t)t * DIN + e];
    P += d;
    float cc = dbc[t * FDIM + DTRANK + NSTATE + s];
    float yp = __expf(a * P) * hin * cc;
    yp += __shfl_xor(yp, 1);
    yp += __shfl_xor(yp, 2);
    yp += __shfl_xor(yp, 4);
    yp += __shfl_xor(yp, 8);
    if (s == 0) {
      float u = uc[(size_t)t * DIN + e];
      float z = xz[(size_t)t * DXZ + DIN + e];
      float y = g_ws[OFF_Y + (size_t)t * DIN + e] + yp;
      float sig = 1.f / (1.f + __expf(-z));
      float v = (y + dsk * u) * z * sig;
      size_t idx = (size_t)t * DIN + e;
      unsigned short h = f2bf(v);
      g_bf[BF_YHI + idx] = h;
      g_bf[BF_YLO + idx] = f2bf(v - bf2f(h));
    }
  }
}

// ---------------- running segment mean (m_current) ----------------
// Also supplies m_stack: m_stack[n][d] == mcur[(n+1)*SEG-1][d] bit-exactly.
__global__ __launch_bounds__(256) void mcurrent_kernel() {
  int n = blockIdx.x / 3;
  int d = (blockIdx.x % 3) * 256 + threadIdx.x;
  const float* __restrict__ x = g_ws + OFF_X + (size_t)n * SEGLEN * DMODEL + d;
  float* __restrict__ mc = g_ws + OFF_MCUR + (size_t)n * SEGLEN * DMODEL + d;
  float run = 0.f;
  for (int i = 0; i < SEGLEN; ++i) {
    run += x[(size_t)i * DMODEL];
    mc[(size_t)i * DMODEL] = run / (float)(i + 1);
  }
}

// ---------------- retention (writes X f32 + hi/lo) ----------------
__global__ __launch_bounds__(256) void retention_kernel() {
  int t = blockIdx.x;
  int tid = threadIdx.x;
  const float* __restrict__ xout = g_ws + OFF_XOUT;
  const float* __restrict__ uret = g_ws + OFF_URET;
  const float* __restrict__ mcur = g_ws + OFF_MCUR;
  __shared__ float red[4][9];
  __shared__ float attn_s[9];
  float p[9];
#pragma unroll
  for (int n = 0; n < 9; ++n) p[n] = 0.f;
#pragma unroll
  for (int j = 0; j < 3; ++j) {
    int d = tid + j * 256;
    float u = uret[(size_t)t * DMODEL + d];
    p[8] = fmaf(u, mcur[(size_t)t * DMODEL + d], p[8]);
#pragma unroll
    for (int n = 0; n < 8; ++n)
      p[n] = fmaf(u, mcur[(size_t)(n * SEGLEN + SEGLEN - 1) * DMODEL + d], p[n]);
  }
#pragma unroll
  for (int off = 32; off > 0; off >>= 1)
#pragma unroll
    for (int n = 0; n < 9; ++n) p[n] += __shfl_down(p[n], off, 64);
  int wave = tid >> 6;
  if ((tid & 63) == 0)
#pragma unroll
    for (int n = 0; n < 9; ++n) red[wave][n] = p[n];
  __syncthreads();
  if (tid == 0) {
    const float scale = 0.03608439182435161f;
    int seg = t >> 8;
    float sc[9], mx = -3.0e38f;
#pragma unroll
    for (int n = 0; n < 9; ++n) {
      float v = (red[0][n] + red[1][n] + red[2][n] + red[3][n]) * scale;
      if (n < 8 && n >= seg) v = -1e30f;
      sc[n] = v;
      mx = fmaxf(mx, v);
    }
    float den = 0.f;
#pragma unroll
    for (int n = 0; n < 9; ++n) {
      float e = __expf(sc[n] - mx);
      sc[n] = e;
      den += e;
    }
    float inv = 1.f / den;
#pragma unroll
    for (int n = 0; n < 9; ++n) attn_s[n] = sc[n] * inv;
  }
  __syncthreads();
  float a[9];
#pragma unroll
  for (int n = 0; n < 9; ++n) a[n] = attn_s[n];
#pragma unroll
  for (int j = 0; j < 3; ++j) {
    int d = tid + j * 256;
    float acc = a[8] * xout[(size_t)t * DMODEL + d];
#pragma unroll
    for (int n = 0; n < 8; ++n)
      acc = fmaf(a[n], xout[(size_t)(n * SEGLEN + SEGLEN - 1) * DMODEL + d], acc);
    size_t idx = (size_t)t * DMODEL + d;
    g_ws[OFF_X + idx] = acc;
    unsigned short h = f2bf(acc);
    g_bf[BF_XHI + idx] = h;
    g_bf[BF_XLO + idx] = f2bf(acc - bf2f(h));
  }
}

extern "C" void kernel_launch(void* const* d_in, const int* in_sizes, int n_in,
                              void* d_out, int out_size, void* d_ws, size_t ws_size,
                              hipStream_t stream) {
  (void)in_sizes; (void)n_in; (void)out_size; (void)d_ws; (void)ws_size;
  const int* tokens = (const int*)d_in[0];

  detect_kernel<<<1, 64, 0, stream>>>((const unsigned int*)d_in[10]);

  convert_all<<<(7219200 + 255) / 256, 256, 0, stream>>>(
      d_in[1], d_in[4], d_in[5], d_in[6], d_in[7], d_in[8], d_in[9], d_in[10]);
  splitw_all<<<(22806528 + 255) / 256, 256, 0, stream>>>(
      d_in[3], d_in[11], d_in[2], d_in[12]);

  embed_kernel<<<T_LEN, 256, 0, stream>>>(tokens);

  for (int l = 0; l < 4; ++l) {
    unsigned int xp = OFF_WXP + (unsigned)l * FDIM * DIN;
    unsigned int dw = OFF_WDW + (unsigned)l * DIN * DTRANK;
    unsigned int db = OFF_WDB + (unsigned)l * DIN;
    unsigned int al = OFF_WAL + (unsigned)l * DIN * NSTATE;
    unsigned int ds = OFF_WDS + (unsigned)l * DIN;
    unsigned int cw = OFF_WCW + (unsigned)l * DIN * 4;
    unsigned int cb = OFF_WCB + (unsigned)l * DIN;
    unsigned int iphi = BF_IPHI + (unsigned)l * DXZ * DMODEL;
    unsigned int iplo = BF_IPLO + (unsigned)l * DXZ * DMODEL;
    unsigned int ophi = BF_OPHI + (unsigned)l * DMODEL * DIN;
    unsigned int oplo = BF_OPLO + (unsigned)l * DMODEL * DIN;
    unsigned int wuhi = BF_WUHI + (unsigned)l * DMODEL * DMODEL;
    unsigned int wulo = BF_WULO + (unsigned)l * DMODEL * DMODEL;

    // xz = x @ in_proj^T   (2048 x 3072, K=768), 24x16 = 384 blocks
    gemm_mfma<128, 0><<<dim3(DXZ / 128, T_LEN / 128), 256, 0, stream>>>(
        BF_XHI, BF_XLO, iphi, iplo, OFF_XZ, nullptr, DXZ, DMODEL);
    conv_silu_kernel<<<(T_LEN * DIN) / 256, 256, 0, stream>>>(cw, cb);
    // dbc = uc @ x_proj^T  (2048 x 80, K=1536)
    gemm_nt<0><<<dim3(2, 32), 256, 0, stream>>>(OFF_UC, DIN, xp, DIN,
                                                OFF_DBC, FDIM, T_LEN, FDIM, DIN, 0u);
    // delta = softplus(dbc[:, :48] @ dt_w^T + dt_b)
    gemm_nt<1><<<dim3(24, 32), 256, 0, stream>>>(OFF_DBC, FDIM, dw, DTRANK,
                                                 OFF_DELTA, DIN, T_LEN, DIN, DTRANK, db);
    // chunked selective scan (phase3 emits y hi/lo directly)
    scan_phase1<<<dim3(DIN / 16, NC), 256, 0, stream>>>(al);
    scan_phase2<<<(DIN * NSTATE) / 256, 256, 0, stream>>>(al);
    scan_phase3<<<dim3(DIN / 16, NC), 256, 0, stream>>>(al, ds);
    // m_current (independent of GEMMs), then fused out_proj + W_u
    mcurrent_kernel<<<NSEG * 3, 256, 0, stream>>>();
    gemm_mid<<<dim3(DMODEL / 64, T_LEN / 128, 2), 256, 0, stream>>>(
        ophi, oplo, wuhi, wulo);
    // retention emits next-layer x hi/lo directly
    retention_kernel<<<T_LEN, 256, 0, stream>>>();
  }

  // logits = x @ head_w^T  (2048 x 8192, K=768), 64x16 = 1024 blocks
  gemm_mfma<128, 2><<<dim3(NHEADV / 128, T_LEN / 128), 256, 0, stream>>>(
      BF_XHI, BF_XLO, BF_HWHI, BF_HWLO, 0u, d_out, NHEADV, DMODEL);
}